// Round 1
// 360.763 us; speedup vs baseline: 1.3423x; 1.3423x over previous
//
#include <hip/hip_runtime.h>

// ---------------------------------------------------------------------------
// LRU single step, fused — v2 (state-based y, single-pass x0).
//   state = Lambda * x0 + Bn @ u              (complex; stored PLANAR re|im)
//   y     = s_re @ C_re^T - s_im @ C_im^T + u @ D^T
// Weights:
//   W1 [1024][256] bf16, chunked-planar: rows s*256+[0,128) = Bn_re[h=s*128+j],
//                                        rows s*256+[128,256) = Bn_im[same h]
//   Wy [256][1280] bf16: cols [0,512)=C_re, [512,1024)=-C_im, [1024,1280)=D
// All preps are elementwise (the old E-GEMM prep is eliminated).
// Main kernel: per 32-row block, 4 chunks of 128 h-columns:
//   GEMM-A (Bu chunk -> LDS f32) -> vectorized epilogue (f32 state, coalesced
//   float4 stores, bf16 state chunk -> LDS) -> partial y-GEMM accumulate.
// ---------------------------------------------------------------------------

typedef __attribute__((ext_vector_type(8))) short bf16x8;
typedef __attribute__((ext_vector_type(4))) float f32x4;
typedef unsigned short u16;

#define N_ROWS 32768
#define IN_DIM 256
#define SD 512
#define OUT_DIM 256
#define ROWS 32          // rows per block
#define NTHR 512         // 8 waves
#define XU_P 264         // u tile pitch (u16)
#define SC_P 264         // state-chunk pitch (u16)
#define BU_P 260         // Bu pitch (f32)

__device__ __align__(16) float g_lam[3 * SD];            // lam_re | lam_im | g
__device__ __align__(16) u16   g_W1[1024 * IN_DIM];      // bf16
__device__ __align__(16) u16   g_Wy[OUT_DIM * 1280];     // bf16

__device__ __forceinline__ u16 f2b(float f) {
    union { float f; unsigned int u; } v; v.f = f;
    unsigned int r = v.u + 0x7FFFu + ((v.u >> 16) & 1u);   // RNE
    return (u16)(r >> 16);
}
__device__ __forceinline__ ushort4 f2b4(f32x4 v) {
    ushort4 b;
    b.x = f2b(v[0]); b.y = f2b(v[1]); b.z = f2b(v[2]); b.w = f2b(v[3]);
    return b;
}

// --- prep 1: lam_re[512], lam_im[512], g[512] -------------------------------
__global__ void prep_lam(const float* __restrict__ nu_log,
                         const float* __restrict__ theta_log,
                         const float* __restrict__ gamma_log) {
    int t = threadIdx.x;
    if (t < SD) {
        float mod = expf(-expf(nu_log[t]));
        float th  = expf(theta_log[t]);
        g_lam[t]        = mod * cosf(th);
        g_lam[SD + t]   = mod * sinf(th);
        g_lam[2*SD + t] = expf(gamma_log[t]);
    }
}

// --- prep 2: W1 bf16, chunked-planar ---------------------------------------
__global__ void prep_W1(const float* __restrict__ B_re, const float* __restrict__ B_im) {
    int r = blockIdx.x;            // [0,1024)
    int k = threadIdx.x;           // [0,256)
    int s = r >> 8, w = r & 255;
    int h = s * 128 + (w & 127);
    float g = g_lam[2*SD + h];
    const float* src = (w < 128) ? B_re : B_im;
    g_W1[r * IN_DIM + k] = f2b(src[h * IN_DIM + k] * g);
}

// --- prep 3: Wy = [C_re | -C_im | D] (pure elementwise) ---------------------
__global__ void prep_Wy(const float* __restrict__ C_re, const float* __restrict__ C_im,
                        const float* __restrict__ D) {
    int o = blockIdx.x;            // [0,256)
    int t = threadIdx.x;           // [0,256)
    #pragma unroll
    for (int it = 0; it < 5; ++it) {
        int c = it * 256 + t;
        float v;
        if (c < 512)       v =  C_re[o * SD + c];
        else if (c < 1024) v = -C_im[o * SD + (c - 512)];
        else               v =  D[o * IN_DIM + (c - 1024)];
        g_Wy[(size_t)o * 1280 + c] = f2b(v);
    }
}

// --- main fused kernel ------------------------------------------------------
__global__ __launch_bounds__(NTHR, 4) void lru_main(
    const float* __restrict__ u, const float* __restrict__ x0_re,
    const float* __restrict__ x0_im,
    float* __restrict__ y_out, float* __restrict__ st_out,
    long long st_limit)     // floats available in the state region of d_out
{
    __shared__ __align__(16) u16   Xu[ROWS * XU_P];   // u tile bf16
    __shared__ __align__(16) u16   Sc[ROWS * SC_P];   // state chunk bf16 (re|im)
    __shared__ __align__(16) float Bu[ROWS * BU_P];   // Bu chunk f32 (re|im)

    const int tid  = threadIdx.x;
    const int wv   = tid >> 6;          // [0,8)
    const int lane = tid & 63;
    const int quad = lane >> 4;
    const int l16  = lane & 15;
    const int kq   = quad * 8;
    const size_t n0 = (size_t)blockIdx.x * ROWS;

    // stage u tile -> bf16 LDS (32x256, float4 loads)
    #pragma unroll
    for (int i = 0; i < 4; ++i) {
        int it = tid + i * NTHR;              // 2048 items
        int r = it >> 6, c4 = it & 63;
        f32x4 v = ((const f32x4*)(u + (n0 + r) * IN_DIM))[c4];
        *(ushort4*)(&Xu[r * XU_P + c4 * 4]) = f2b4(v);
    }
    __syncthreads();

    f32x4 accy[2][2];
    #pragma unroll
    for (int mt = 0; mt < 2; ++mt)
        #pragma unroll
        for (int ct = 0; ct < 2; ++ct)
            accy[mt][ct] = f32x4{0.f, 0.f, 0.f, 0.f};

    for (int s = 0; s < 4; ++s) {
        // prefetch x0 (f32x4, coalesced) — consumed after GEMM-A
        f32x4 xr[2], xi[2];
        int nn[2], jj[2];
        #pragma unroll
        for (int it = 0; it < 2; ++it) {
            int flat = it * NTHR + tid;       // [0,1024)
            nn[it] = flat >> 5; jj[it] = flat & 31;
            size_t off = (n0 + nn[it]) * SD + s * 128 + jj[it] * 4;
            xr[it] = *(const f32x4*)(x0_re + off);
            xi[it] = *(const f32x4*)(x0_im + off);
        }

        // ---- GEMM-A: Bu[32][256] = u_tile @ W1_chunk^T  (wave -> 32 cols)
        f32x4 acc[2][2];
        #pragma unroll
        for (int mt = 0; mt < 2; ++mt)
            #pragma unroll
            for (int ct = 0; ct < 2; ++ct)
                acc[mt][ct] = f32x4{0.f, 0.f, 0.f, 0.f};
        const u16* w1b = g_W1 + (size_t)(s * 256 + wv * 32) * IN_DIM;
        #pragma unroll
        for (int k0 = 0; k0 < IN_DIM; k0 += 32) {
            bf16x8 a[2], b[2];
            #pragma unroll
            for (int mt = 0; mt < 2; ++mt)
                a[mt] = *(const bf16x8*)(&Xu[(mt * 16 + l16) * XU_P + k0 + kq]);
            #pragma unroll
            for (int ct = 0; ct < 2; ++ct)
                b[ct] = *(const bf16x8*)(w1b + (ct * 16 + l16) * IN_DIM + k0 + kq);
            #pragma unroll
            for (int mt = 0; mt < 2; ++mt)
                #pragma unroll
                for (int ct = 0; ct < 2; ++ct)
                    acc[mt][ct] = __builtin_amdgcn_mfma_f32_16x16x32_bf16(
                        a[mt], b[ct], acc[mt][ct], 0, 0, 0);
        }
        #pragma unroll
        for (int mt = 0; mt < 2; ++mt)
            #pragma unroll
            for (int ct = 0; ct < 2; ++ct)
                #pragma unroll
                for (int r = 0; r < 4; ++r)
                    Bu[(mt * 16 + quad * 4 + r) * BU_P + wv * 32 + ct * 16 + l16]
                        = acc[mt][ct][r];
        __syncthreads();

        // ---- epilogue: state = lam*x0 + Bu; store f32 planar; bf16 -> Sc
        #pragma unroll
        for (int it = 0; it < 2; ++it) {
            int n = nn[it], j4 = jj[it];
            f32x4 br  = *(const f32x4*)(&Bu[n * BU_P + j4 * 4]);
            f32x4 bi  = *(const f32x4*)(&Bu[n * BU_P + 128 + j4 * 4]);
            f32x4 lre = *(const f32x4*)(g_lam + s * 128 + j4 * 4);
            f32x4 lim = *(const f32x4*)(g_lam + SD + s * 128 + j4 * 4);
            f32x4 sr = lre * xr[it] - lim * xi[it] + br;
            f32x4 si = lre * xi[it] + lim * xr[it] + bi;
            long long ir = (long long)((n0 + n) * SD + s * 128 + j4 * 4);
            long long ii = (long long)N_ROWS * SD + ir;
            if (ir + 3 < st_limit) { *(f32x4*)(st_out + ir) = sr; }
            else {
                #pragma unroll
                for (int k = 0; k < 4; ++k)
                    if (ir + k < st_limit) st_out[ir + k] = sr[k];
            }
            if (ii + 3 < st_limit) { *(f32x4*)(st_out + ii) = si; }
            else {
                #pragma unroll
                for (int k = 0; k < 4; ++k)
                    if (ii + k < st_limit) st_out[ii + k] = si[k];
            }
            *(ushort4*)(&Sc[n * SC_P + j4 * 4])       = f2b4(sr);
            *(ushort4*)(&Sc[n * SC_P + 128 + j4 * 4]) = f2b4(si);
        }
        __syncthreads();

        // ---- partial y-GEMM: accy += Sc @ Wy_chunk^T
        // Sc cols [0,128) = s_re(h)  -> Wy col  s*128+c
        // Sc cols [128,256) = s_im(h)-> Wy col  512+s*128+(c-128)
        #pragma unroll
        for (int k0 = 0; k0 < 128; k0 += 32) {
            bf16x8 a[2], b[2];
            #pragma unroll
            for (int mt = 0; mt < 2; ++mt)
                a[mt] = *(const bf16x8*)(&Sc[(mt * 16 + l16) * SC_P + k0 + kq]);
            #pragma unroll
            for (int ct = 0; ct < 2; ++ct)
                b[ct] = *(const bf16x8*)(g_Wy
                        + (size_t)(wv * 32 + ct * 16 + l16) * 1280
                        + s * 128 + k0 + kq);
            #pragma unroll
            for (int mt = 0; mt < 2; ++mt)
                #pragma unroll
                for (int ct = 0; ct < 2; ++ct)
                    accy[mt][ct] = __builtin_amdgcn_mfma_f32_16x16x32_bf16(
                        a[mt], b[ct], accy[mt][ct], 0, 0, 0);
        }
        #pragma unroll
        for (int k0 = 128; k0 < 256; k0 += 32) {
            bf16x8 a[2], b[2];
            #pragma unroll
            for (int mt = 0; mt < 2; ++mt)
                a[mt] = *(const bf16x8*)(&Sc[(mt * 16 + l16) * SC_P + k0 + kq]);
            #pragma unroll
            for (int ct = 0; ct < 2; ++ct)
                b[ct] = *(const bf16x8*)(g_Wy
                        + (size_t)(wv * 32 + ct * 16 + l16) * 1280
                        + 384 + s * 128 + k0 + kq);   // 512 + s*128 + (k0-128)
            #pragma unroll
            for (int mt = 0; mt < 2; ++mt)
                #pragma unroll
                for (int ct = 0; ct < 2; ++ct)
                    accy[mt][ct] = __builtin_amdgcn_mfma_f32_16x16x32_bf16(
                        a[mt], b[ct], accy[mt][ct], 0, 0, 0);
        }
        // next iteration: GEMM-A writes Bu (readers synced), epilogue writes Sc
        // only after the barrier following GEMM-A's fragment writes.
    }

    // ---- y u-part: accy += u_tile @ D^T
    #pragma unroll
    for (int k0 = 0; k0 < IN_DIM; k0 += 32) {
        bf16x8 a[2], b[2];
        #pragma unroll
        for (int mt = 0; mt < 2; ++mt)
            a[mt] = *(const bf16x8*)(&Xu[(mt * 16 + l16) * XU_P + k0 + kq]);
        #pragma unroll
        for (int ct = 0; ct < 2; ++ct)
            b[ct] = *(const bf16x8*)(g_Wy
                    + (size_t)(wv * 32 + ct * 16 + l16) * 1280
                    + 1024 + k0 + kq);
        #pragma unroll
        for (int mt = 0; mt < 2; ++mt)
            #pragma unroll
            for (int ct = 0; ct < 2; ++ct)
                accy[mt][ct] = __builtin_amdgcn_mfma_f32_16x16x32_bf16(
                    a[mt], b[ct], accy[mt][ct], 0, 0, 0);
    }

    // ---- y epilogue: fragments -> Bu (transpose buffer) -> coalesced store
    // (all Bu readers passed the barrier before the last y-GEMM; safe to write)
    #pragma unroll
    for (int mt = 0; mt < 2; ++mt)
        #pragma unroll
        for (int ct = 0; ct < 2; ++ct)
            #pragma unroll
            for (int r = 0; r < 4; ++r)
                Bu[(mt * 16 + quad * 4 + r) * BU_P + wv * 32 + ct * 16 + l16]
                    = accy[mt][ct][r];
    __syncthreads();
    #pragma unroll
    for (int i = 0; i < 4; ++i) {
        int it = tid + i * NTHR;                  // 2048 items
        int r = it >> 6, c4 = it & 63;
        f32x4 v = *(const f32x4*)(&Bu[r * BU_P + c4 * 4]);
        *(f32x4*)(y_out + (n0 + r) * OUT_DIM + c4 * 4) = v;
    }
}

extern "C" void kernel_launch(void* const* d_in, const int* in_sizes, int n_in,
                              void* d_out, int out_size, void* d_ws, size_t ws_size,
                              hipStream_t stream) {
    const float* u         = (const float*)d_in[0];
    const float* x0_re     = (const float*)d_in[1];
    const float* x0_im     = (const float*)d_in[2];
    const float* nu_log    = (const float*)d_in[3];
    const float* theta_log = (const float*)d_in[4];
    const float* gamma_log = (const float*)d_in[5];
    const float* B_re      = (const float*)d_in[6];
    const float* B_im      = (const float*)d_in[7];
    const float* C_re      = (const float*)d_in[8];
    const float* C_im      = (const float*)d_in[9];
    const float* D         = (const float*)d_in[10];

    float* y_out  = (float*)d_out;
    float* st_out = y_out + (size_t)N_ROWS * OUT_DIM;
    long long st_limit = (long long)out_size - (long long)N_ROWS * OUT_DIM;

    prep_lam<<<1, 512, 0, stream>>>(nu_log, theta_log, gamma_log);
    prep_W1<<<1024, 256, 0, stream>>>(B_re, B_im);
    prep_Wy<<<256, 256, 0, stream>>>(C_re, C_im, D);
    lru_main<<<N_ROWS / ROWS, NTHR, 0, stream>>>(u, x0_re, x0_im, y_out, st_out, st_limit);
}